// Round 7
// baseline (39.549 us; speedup 1.0000x reference)
//
#include <hip/hip_runtime.h>

#define S_DIM  2048
#define B_DIM  1024
#define SC_DIM 4096

#define BM 128
#define BN 128
#define BK 64

typedef __bf16 bf16x8 __attribute__((ext_vector_type(8)));
typedef float  f32x4  __attribute__((ext_vector_type(4)));
typedef unsigned short u16x4 __attribute__((ext_vector_type(4)));
typedef unsigned short u16x8 __attribute__((ext_vector_type(8)));

__device__ __forceinline__ unsigned short f2bf(float f) {
    unsigned int u = __builtin_bit_cast(unsigned int, f);
    return (unsigned short)((u + 0x7FFFu + ((u >> 16) & 1u)) >> 16);
}

__device__ __forceinline__ void gld_lds16(const void* g, void* l) {
    __builtin_amdgcn_global_load_lds(
        (const __attribute__((address_space(1))) unsigned int*)g,
        (__attribute__((address_space(3))) unsigned int*)l, 16, 0, 0);
}

// ---------------- fused prepack ----------------
// blocks [0,1024):  wsA packed in MFMA-frag order:
//   wsA[((mg*32 + kb)*64 + lane)*8 + j] = bf16(cm*p)[row = mg*16 + (lane&15)][k = kb*32 + (lane>>4)*8 + j]
// blocks [1024,1536): wsB[n][k] = bf16(bsc[k][n]), 16B-chunk-swizzled (chunk g at g^(n&7))
__global__ __launch_bounds__(256)
void prepack_ab(const float* __restrict__ proba,
                const float* __restrict__ avail,
                const float* __restrict__ alloc,
                const float* __restrict__ bsc,
                unsigned short* __restrict__ wsA,
                unsigned short* __restrict__ wsB)
{
    __shared__ float lds[64][129];
    const int t = threadIdx.x;

    if (blockIdx.x < 1024) {
        int c = blockIdx.x * 256 + t;        // 0 .. 262143
        int lane = c & 63;
        int fragslot = c >> 6;               // mg*32 + kb
        int mg = fragslot >> 5;
        int kb = fragslot & 31;
        int l16 = lane & 15;
        int lg  = lane >> 4;
        int row = mg * 16 + l16;
        int k   = kb * 32 + lg * 8;

        f32x4 p0 = *(const f32x4*)&proba[(size_t)row * B_DIM + k];
        f32x4 p1 = *(const f32x4*)&proba[(size_t)row * B_DIM + k + 4];
        f32x4 av0 = *(const f32x4*)&avail[k];
        f32x4 av1 = *(const f32x4*)&avail[k + 4];
        f32x4 al0 = *(const f32x4*)&alloc[k];
        f32x4 al1 = *(const f32x4*)&alloc[k + 4];

        u16x8 w;
        #pragma unroll
        for (int i = 0; i < 4; ++i) {
            float pv = p0[i];
            bool oa = (av0[i] - pv < 0.f) && (pv > 0.f);
            bool ob = (al0[i] + pv < 0.f) && (pv < 0.f);
            w[i] = f2bf(pv * ((oa || ob) ? 0.01f : 1.0f));
        }
        #pragma unroll
        for (int i = 0; i < 4; ++i) {
            float pv = p1[i];
            bool oa = (av1[i] - pv < 0.f) && (pv > 0.f);
            bool ob = (al1[i] + pv < 0.f) && (pv < 0.f);
            w[4 + i] = f2bf(pv * ((oa || ob) ? 0.01f : 1.0f));
        }
        *(u16x8*)&wsA[(size_t)c * 8] = w;    // fully coalesced
    } else {
        int b2 = blockIdx.x - 1024;           // 0..511
        const int bn0 = (b2 & 31) * 128;
        const int k0  = (b2 >> 5) * 64;

        #pragma unroll
        for (int p = 0; p < 8; ++p) {
            int kl = (t >> 5) + p * 8;
            int cl = (t & 31) * 4;
            f32x4 v = *(const f32x4*)&bsc[(size_t)(k0 + kl) * SC_DIM + bn0 + cl];
            lds[kl][cl]     = v[0];
            lds[kl][cl + 1] = v[1];
            lds[kl][cl + 2] = v[2];
            lds[kl][cl + 3] = v[3];
        }
        __syncthreads();

        #pragma unroll
        for (int p = 0; p < 4; ++p) {
            int g = t & 7;
            int n = (t >> 3) + p * 32;
            u16x8 w;
            #pragma unroll
            for (int i = 0; i < 8; ++i)
                w[i] = f2bf(lds[g * 8 + i][n]);
            int gs = g ^ (n & 7);
            *(u16x8*)&wsB[(size_t)(bn0 + n) * B_DIM + k0 + gs * 8] = w;
        }
    }
}

// ---------------- main GEMM: A direct from frag-packed ws (reg prefetch), B via LDS ----------------
__global__ __launch_bounds__(256, 2)
void gemm_pk(const unsigned short* __restrict__ wsA,
             const unsigned short* __restrict__ wsB,
             const float* __restrict__ cur,
             float* __restrict__ out)
{
    __shared__ __align__(16) unsigned short sB[BN * BK];   // 16 KB

    const int tid  = threadIdx.x;
    const int lane = tid & 63;
    const int wid  = tid >> 6;          // 0..3
    const int wm   = wid >> 1;          // 0..1 : 64-row slice
    const int wn   = wid & 1;           // 0..1 : 64-col slice
    const int l16  = lane & 15;
    const int lg   = lane >> 4;

    // XCD ownership: XCD x owns n-tiles [4x,4x+4) -> per-XCD B slice 1MB (L2-resident)
    const int bid    = blockIdx.x;
    const int x      = bid & 7;
    const int l      = bid >> 3;        // 0..63
    const int n_tile = x * 4 + (l & 3); // 0..31
    const int m_tile = l >> 2;          // 0..15
    const int bm0    = m_tile * BM;
    const int bn0    = n_tile * BN;

    const int crow = tid >> 3;          // 0..31
    const int cg   = tid & 7;

    const int mgBase = (bm0 >> 4) + wm * 4;   // row-group base for this wave's 64-row slice

    f32x4 acc[4][4];
    #pragma unroll
    for (int i = 0; i < 4; ++i)
        #pragma unroll
        for (int j = 0; j < 4; ++j)
            acc[i][j] = {0.f, 0.f, 0.f, 0.f};

    auto stageB = [&](int k0) {
        #pragma unroll
        for (int is = 0; is < 4; ++is)
            gld_lds16(wsB + (size_t)(bn0 + is * 32 + crow) * B_DIM + k0 + cg * 8,
                      &sB[(is * 256 + tid) * 8]);
    };

    // A frag (mf, kb) at: wsA + ((mgBase+mf)*32 + kb)*512 + lane*8   (elems)
    const unsigned short* aBase = wsA + ((size_t)mgBase * 32 * 64 + lane) * 8;

    auto loadA = [&](int t, bf16x8 (&dst)[2][4]) {
        #pragma unroll
        for (int kk = 0; kk < 2; ++kk)
            #pragma unroll
            for (int mf = 0; mf < 4; ++mf)
                dst[kk][mf] = *(const bf16x8*)(aBase + ((size_t)(mf * 32 + 2 * t + kk)) * 512);
    };

    bf16x8 aP[2][4], aQ[2][4];

    stageB(0);
    loadA(0, aP);

    auto body = [&](int t, bf16x8 (&acur)[2][4], bf16x8 (&anxt)[2][4]) {
        __syncthreads();                 // stage(t) + A(t) landed (vmcnt0)

        bf16x8 bfr[2][4];
        #pragma unroll
        for (int kk = 0; kk < 2; ++kk)
            #pragma unroll
            for (int nf = 0; nf < 4; ++nf) {
                int r = wn * 64 + nf * 16 + l16;
                bfr[kk][nf] = *(const bf16x8*)&sB[r * BK + (((kk * 4 + lg) ^ (r & 7)) * 8)];
            }
        __syncthreads();                 // all reads done, sB free

        if (t < B_DIM / BK - 1) {
            stageB((t + 1) * BK);        // 4 gld_lds fly under the MFMA cluster
            loadA(t + 1, anxt);          // 8 reg loads fly under the MFMA cluster
        }
        __builtin_amdgcn_sched_barrier(0);  // keep MFMAs below the load issue

        #pragma unroll
        for (int kk = 0; kk < 2; ++kk)
            #pragma unroll
            for (int mf = 0; mf < 4; ++mf)
                #pragma unroll
                for (int nf = 0; nf < 4; ++nf)
                    acc[mf][nf] = __builtin_amdgcn_mfma_f32_16x16x32_bf16(
                        acur[kk][mf], bfr[kk][nf], acc[mf][nf], 0, 0, 0);
    };

    for (int tt = 0; tt < B_DIM / BK / 2; ++tt) {   // 8 double-steps, static reg roles
        body(2 * tt,     aP, aQ);
        body(2 * tt + 1, aQ, aP);
    }

    // epilogue: out = cur + acc
    #pragma unroll
    for (int mf = 0; mf < 4; ++mf)
        #pragma unroll
        for (int j = 0; j < 4; ++j)
            #pragma unroll
            for (int nf = 0; nf < 4; ++nf) {
                int row = bm0 + wm * 64 + mf * 16 + lg * 4 + j;
                int col = bn0 + wn * 64 + nf * 16 + l16;
                size_t idx = (size_t)row * SC_DIM + col;
                out[idx] = cur[idx] + acc[mf][nf][j];
            }
}

// ---------------- fallback (fused single-pass), used only if ws too small ----------------
#define FBM 128
#define FBN 128
#define LDK 72
__global__ __launch_bounds__(256, 2)
void opt_gemm_fused(const float* __restrict__ proba,
                    const float* __restrict__ cur,
                    const float* __restrict__ bsc,
                    const float* __restrict__ avail,
                    const float* __restrict__ alloc,
                    float* __restrict__ out)
{
    __shared__ __align__(16) unsigned short sA[FBM * LDK];
    __shared__ __align__(16) unsigned short sB[FBN * LDK];
    const int tid = threadIdx.x;
    const int lane = tid & 63;
    const int wid = tid >> 6;
    const int wm = wid >> 1, wn = wid & 1;
    const int bm0 = blockIdx.y * FBM, bn0 = blockIdx.x * FBN;
    const int af4 = tid & 15, ar0 = tid >> 4;
    const int bnn = tid & 127, bkh = tid >> 7;
    const int l16 = lane & 15, lg = lane >> 4;

    f32x4 acc[4][4];
    #pragma unroll
    for (int i = 0; i < 4; ++i)
        #pragma unroll
        for (int j = 0; j < 4; ++j) acc[i][j] = {0.f, 0.f, 0.f, 0.f};

    for (int k0 = 0; k0 < B_DIM; k0 += BK) {
        f32x4 av = *(const f32x4*)&avail[k0 + af4 * 4];
        f32x4 al = *(const f32x4*)&alloc[k0 + af4 * 4];
        #pragma unroll
        for (int pass = 0; pass < 8; ++pass) {
            int r = ar0 + pass * 16;
            f32x4 p = *(const f32x4*)&proba[(size_t)(bm0 + r) * B_DIM + k0 + af4 * 4];
            u16x4 w;
            #pragma unroll
            for (int i = 0; i < 4; ++i) {
                float pv = p[i];
                bool oa = (av[i] - pv < 0.f) && (pv > 0.f);
                bool ob = (al[i] + pv < 0.f) && (pv < 0.f);
                w[i] = f2bf(pv * ((oa || ob) ? 0.01f : 1.0f));
            }
            *(u16x4*)&sA[r * LDK + af4 * 4] = w;
        }
        #pragma unroll
        for (int g = 0; g < 4; ++g) {
            u16x8 w;
            #pragma unroll
            for (int i = 0; i < 8; ++i) {
                int kk = bkh * 32 + g * 8 + i;
                w[i] = f2bf(bsc[(size_t)(k0 + kk) * SC_DIM + bn0 + bnn]);
            }
            *(u16x8*)&sB[bnn * LDK + bkh * 32 + g * 8] = w;
        }
        __syncthreads();
        #pragma unroll
        for (int kk = 0; kk < 2; ++kk) {
            bf16x8 afr[4], bfr[4];
            #pragma unroll
            for (int mf = 0; mf < 4; ++mf)
                afr[mf] = *(const bf16x8*)&sA[(wm * 64 + mf * 16 + l16) * LDK + kk * 32 + lg * 8];
            #pragma unroll
            for (int nf = 0; nf < 4; ++nf)
                bfr[nf] = *(const bf16x8*)&sB[(wn * 64 + nf * 16 + l16) * LDK + kk * 32 + lg * 8];
            #pragma unroll
            for (int mf = 0; mf < 4; ++mf)
                #pragma unroll
                for (int nf = 0; nf < 4; ++nf)
                    acc[mf][nf] = __builtin_amdgcn_mfma_f32_16x16x32_bf16(
                        afr[mf], bfr[nf], acc[mf][nf], 0, 0, 0);
        }
        __syncthreads();
    }
    #pragma unroll
    for (int mf = 0; mf < 4; ++mf)
        #pragma unroll
        for (int j = 0; j < 4; ++j) {
            int row = bm0 + wm * 64 + mf * 16 + lg * 4 + j;
            #pragma unroll
            for (int nf = 0; nf < 4; ++nf) {
                int col = bn0 + wn * 64 + nf * 16 + l16;
                size_t idx = (size_t)row * SC_DIM + col;
                out[idx] = cur[idx] + acc[mf][nf][j];
            }
        }
}

extern "C" void kernel_launch(void* const* d_in, const int* in_sizes, int n_in,
                              void* d_out, int out_size, void* d_ws, size_t ws_size,
                              hipStream_t stream) {
    const float* proba = (const float*)d_in[0];
    const float* cur   = (const float*)d_in[1];
    const float* bsc   = (const float*)d_in[2];
    const float* avail = (const float*)d_in[3];
    const float* alloc = (const float*)d_in[4];
    float* out = (float*)d_out;

    const size_t wsA_bytes = (size_t)S_DIM * B_DIM * 2;   // 4 MB
    const size_t wsB_bytes = (size_t)SC_DIM * B_DIM * 2;  // 8 MB

    if (ws_size >= wsA_bytes + wsB_bytes) {
        unsigned short* wsA = (unsigned short*)d_ws;
        unsigned short* wsB = (unsigned short*)((char*)d_ws + wsA_bytes);

        prepack_ab<<<dim3(1024 + 512), 256, 0, stream>>>(proba, avail, alloc, bsc, wsA, wsB);
        gemm_pk<<<dim3((S_DIM / BM) * (SC_DIM / BN)), 256, 0, stream>>>(wsA, wsB, cur, out);
    } else {
        opt_gemm_fused<<<dim3(SC_DIM / FBN, S_DIM / FBM), 256, 0, stream>>>(
            proba, cur, bsc, avail, alloc, out);
    }
}

// Round 8
// 35.695 us; speedup vs baseline: 1.1080x; 1.1080x over previous
//
#include <hip/hip_runtime.h>

#define S_DIM  2048
#define B_DIM  1024
#define SC_DIM 4096

#define BM 128
#define BN 128
#define BK 64

typedef __bf16 bf16x8 __attribute__((ext_vector_type(8)));
typedef float  f32x4  __attribute__((ext_vector_type(4)));
typedef unsigned short u16x4 __attribute__((ext_vector_type(4)));
typedef unsigned short u16x8 __attribute__((ext_vector_type(8)));

__device__ __forceinline__ unsigned short f2bf(float f) {
    unsigned int u = __builtin_bit_cast(unsigned int, f);
    return (unsigned short)((u + 0x7FFFu + ((u >> 16) & 1u)) >> 16);
}

__device__ __forceinline__ void gld_lds16(const void* g, void* l) {
    __builtin_amdgcn_global_load_lds(
        (const __attribute__((address_space(1))) unsigned int*)g,
        (__attribute__((address_space(3))) unsigned int*)l, 16, 0, 0);
}

// ---------------- fused prepack (R6 layout) ----------------
// blocks [0,1024):  wsA[n][k] = bf16(proba*cm), 16B-chunk-swizzled (chunk G -> (G&~7)|((G&7)^(n&7)))
// blocks [1024,1536): wsB[n][k] = bf16(bsc[k][n]) transposed, same swizzle
__global__ __launch_bounds__(256)
void prepack_ab(const float* __restrict__ proba,
                const float* __restrict__ avail,
                const float* __restrict__ alloc,
                const float* __restrict__ bsc,
                unsigned short* __restrict__ wsA,
                unsigned short* __restrict__ wsB)
{
    __shared__ float lds[64][129];
    const int t = threadIdx.x;

    if (blockIdx.x < 1024) {
        int c = blockIdx.x * 256 + t;
        int n = c >> 7;
        int G = c & 127;
        int k = G * 8;

        f32x4 p0 = *(const f32x4*)&proba[(size_t)n * B_DIM + k];
        f32x4 p1 = *(const f32x4*)&proba[(size_t)n * B_DIM + k + 4];
        f32x4 av0 = *(const f32x4*)&avail[k];
        f32x4 av1 = *(const f32x4*)&avail[k + 4];
        f32x4 al0 = *(const f32x4*)&alloc[k];
        f32x4 al1 = *(const f32x4*)&alloc[k + 4];

        u16x8 w;
        #pragma unroll
        for (int i = 0; i < 4; ++i) {
            float pv = p0[i];
            bool oa = (av0[i] - pv < 0.f) && (pv > 0.f);
            bool ob = (al0[i] + pv < 0.f) && (pv < 0.f);
            w[i] = f2bf(pv * ((oa || ob) ? 0.01f : 1.0f));
        }
        #pragma unroll
        for (int i = 0; i < 4; ++i) {
            float pv = p1[i];
            bool oa = (av1[i] - pv < 0.f) && (pv > 0.f);
            bool ob = (al1[i] + pv < 0.f) && (pv < 0.f);
            w[4 + i] = f2bf(pv * ((oa || ob) ? 0.01f : 1.0f));
        }
        int Gs = (G & ~7) | ((G & 7) ^ (n & 7));
        *(u16x8*)&wsA[(size_t)n * B_DIM + Gs * 8] = w;
    } else {
        int b2 = blockIdx.x - 1024;
        const int bn0 = (b2 & 31) * 128;
        const int k0  = (b2 >> 5) * 64;

        #pragma unroll
        for (int p = 0; p < 8; ++p) {
            int kl = (t >> 5) + p * 8;
            int cl = (t & 31) * 4;
            f32x4 v = *(const f32x4*)&bsc[(size_t)(k0 + kl) * SC_DIM + bn0 + cl];
            lds[kl][cl]     = v[0];
            lds[kl][cl + 1] = v[1];
            lds[kl][cl + 2] = v[2];
            lds[kl][cl + 3] = v[3];
        }
        __syncthreads();

        #pragma unroll
        for (int p = 0; p < 4; ++p) {
            int g = t & 7;
            int n = (t >> 3) + p * 32;
            u16x8 w;
            #pragma unroll
            for (int i = 0; i < 8; ++i)
                w[i] = f2bf(lds[g * 8 + i][n]);
            int gs = g ^ (n & 7);
            *(u16x8*)&wsB[(size_t)(bn0 + n) * B_DIM + k0 + gs * 8] = w;
        }
    }
}

// ---------------- main GEMM: R6 structure + cur folded into acc during K-loop ----------------
__global__ __launch_bounds__(256, 2)
void gemm_pk(const unsigned short* __restrict__ wsA,
             const unsigned short* __restrict__ wsB,
             const float* __restrict__ cur,
             float* __restrict__ out)
{
    __shared__ __align__(16) unsigned short sA[BM * BK];   // 16 KB
    __shared__ __align__(16) unsigned short sB[BN * BK];   // 16 KB

    const int tid  = threadIdx.x;
    const int lane = tid & 63;
    const int wid  = tid >> 6;          // 0..3
    const int wm   = wid >> 1;          // 0..1 : 64-row slice
    const int wn   = wid & 1;           // 0..1 : 64-col slice
    const int l16  = lane & 15;
    const int lg   = lane >> 4;

    // XCD ownership: XCD x owns n-tiles [4x,4x+4) -> per-XCD B slice 1MB (L2-resident)
    const int bid    = blockIdx.x;
    const int x      = bid & 7;
    const int l      = bid >> 3;
    const int n_tile = x * 4 + (l & 3);
    const int m_tile = l >> 2;
    const int bm0    = m_tile * BM;
    const int bn0    = n_tile * BN;

    const int crow = tid >> 3;
    const int cg   = tid & 7;

    f32x4 acc[4][4];
    #pragma unroll
    for (int i = 0; i < 4; ++i)
        #pragma unroll
        for (int j = 0; j < 4; ++j)
            acc[i][j] = {0.f, 0.f, 0.f, 0.f};

    auto stage = [&](int k0) {
        #pragma unroll
        for (int is = 0; is < 4; ++is)
            gld_lds16(wsA + (size_t)(bm0 + is * 32 + crow) * B_DIM + k0 + cg * 8,
                      &sA[(is * 256 + tid) * 8]);
        #pragma unroll
        for (int is = 0; is < 4; ++is)
            gld_lds16(wsB + (size_t)(bn0 + is * 32 + crow) * B_DIM + k0 + cg * 8,
                      &sB[(is * 256 + tid) * 8]);
    };

    stage(0);

    float cpre[2][4];   // 2 slots x 4 rows, in flight across one iteration

    #pragma unroll
    for (int t = 0; t < 16; ++t) {
        __syncthreads();                 // vmcnt(0): stage(t) + cur loads (t-1) landed

        // fold previously loaded cur values into acc (MFMA accumulates on top)
        if (t >= 8) {
            #pragma unroll
            for (int u = 0; u < 2; ++u) {
                const int s  = 2 * (t - 8) + u;
                const int mf = s >> 2, nf = s & 3;
                #pragma unroll
                for (int j = 0; j < 4; ++j)
                    acc[mf][nf][j] += cpre[u][j];
            }
        }

        // read ALL fragments for this K-step into registers
        bf16x8 afr[2][4], bfr[2][4];
        #pragma unroll
        for (int kk = 0; kk < 2; ++kk) {
            #pragma unroll
            for (int mf = 0; mf < 4; ++mf) {
                int r = wm * 64 + mf * 16 + l16;
                afr[kk][mf] = *(const bf16x8*)&sA[r * BK + (((kk * 4 + lg) ^ (r & 7)) * 8)];
            }
            #pragma unroll
            for (int nf = 0; nf < 4; ++nf) {
                int r = wn * 64 + nf * 16 + l16;
                bfr[kk][nf] = *(const bf16x8*)&sB[r * BK + (((kk * 4 + lg) ^ (r & 7)) * 8)];
            }
        }
        __syncthreads();                 // all LDS reads done, buffers free

        if (t < 15)
            stage((t + 1) * BK);         // 8 gld_lds fly under the MFMA cluster

        if (t >= 7 && t < 15) {          // 8 cur loads fly under the MFMA cluster
            #pragma unroll
            for (int u = 0; u < 2; ++u) {
                const int s   = 2 * (t - 7) + u;
                const int mf  = s >> 2, nf = s & 3;
                const int row = bm0 + wm * 64 + mf * 16 + lg * 4;
                const int col = bn0 + wn * 64 + nf * 16 + l16;
                #pragma unroll
                for (int j = 0; j < 4; ++j)
                    cpre[u][j] = cur[(size_t)(row + j) * SC_DIM + col];
            }
        }
        __builtin_amdgcn_sched_barrier(0);  // keep MFMAs below the load issue

        #pragma unroll
        for (int kk = 0; kk < 2; ++kk)
            #pragma unroll
            for (int mf = 0; mf < 4; ++mf)
                #pragma unroll
                for (int nf = 0; nf < 4; ++nf)
                    acc[mf][nf] = __builtin_amdgcn_mfma_f32_16x16x32_bf16(
                        afr[kk][mf], bfr[kk][nf], acc[kk ? mf : mf][nf], 0, 0, 0);
    }

    // store-only epilogue
    #pragma unroll
    for (int mf = 0; mf < 4; ++mf)
        #pragma unroll
        for (int j = 0; j < 4; ++j)
            #pragma unroll
            for (int nf = 0; nf < 4; ++nf) {
                int row = bm0 + wm * 64 + mf * 16 + lg * 4 + j;
                int col = bn0 + wn * 64 + nf * 16 + l16;
                out[(size_t)row * SC_DIM + col] = acc[mf][nf][j];
            }
}

// ---------------- fallback (fused single-pass), used only if ws too small ----------------
#define FBM 128
#define FBN 128
#define LDK 72
__global__ __launch_bounds__(256, 2)
void opt_gemm_fused(const float* __restrict__ proba,
                    const float* __restrict__ cur,
                    const float* __restrict__ bsc,
                    const float* __restrict__ avail,
                    const float* __restrict__ alloc,
                    float* __restrict__ out)
{
    __shared__ __align__(16) unsigned short sA[FBM * LDK];
    __shared__ __align__(16) unsigned short sB[FBN * LDK];
    const int tid = threadIdx.x;
    const int lane = tid & 63;
    const int wid = tid >> 6;
    const int wm = wid >> 1, wn = wid & 1;
    const int bm0 = blockIdx.y * FBM, bn0 = blockIdx.x * FBN;
    const int af4 = tid & 15, ar0 = tid >> 4;
    const int bnn = tid & 127, bkh = tid >> 7;
    const int l16 = lane & 15, lg = lane >> 4;

    f32x4 acc[4][4];
    #pragma unroll
    for (int i = 0; i < 4; ++i)
        #pragma unroll
        for (int j = 0; j < 4; ++j) acc[i][j] = {0.f, 0.f, 0.f, 0.f};

    for (int k0 = 0; k0 < B_DIM; k0 += BK) {
        f32x4 av = *(const f32x4*)&avail[k0 + af4 * 4];
        f32x4 al = *(const f32x4*)&alloc[k0 + af4 * 4];
        #pragma unroll
        for (int pass = 0; pass < 8; ++pass) {
            int r = ar0 + pass * 16;
            f32x4 p = *(const f32x4*)&proba[(size_t)(bm0 + r) * B_DIM + k0 + af4 * 4];
            u16x4 w;
            #pragma unroll
            for (int i = 0; i < 4; ++i) {
                float pv = p[i];
                bool oa = (av[i] - pv < 0.f) && (pv > 0.f);
                bool ob = (al[i] + pv < 0.f) && (pv < 0.f);
                w[i] = f2bf(pv * ((oa || ob) ? 0.01f : 1.0f));
            }
            *(u16x4*)&sA[r * LDK + af4 * 4] = w;
        }
        #pragma unroll
        for (int g = 0; g < 4; ++g) {
            u16x8 w;
            #pragma unroll
            for (int i = 0; i < 8; ++i) {
                int kk = bkh * 32 + g * 8 + i;
                w[i] = f2bf(bsc[(size_t)(k0 + kk) * SC_DIM + bn0 + bnn]);
            }
            *(u16x8*)&sB[bnn * LDK + bkh * 32 + g * 8] = w;
        }
        __syncthreads();
        #pragma unroll
        for (int kk = 0; kk < 2; ++kk) {
            bf16x8 afr[4], bfr[4];
            #pragma unroll
            for (int mf = 0; mf < 4; ++mf)
                afr[mf] = *(const bf16x8*)&sA[(wm * 64 + mf * 16 + l16) * LDK + kk * 32 + lg * 8];
            #pragma unroll
            for (int nf = 0; nf < 4; ++nf)
                bfr[nf] = *(const bf16x8*)&sB[(wn * 64 + nf * 16 + l16) * LDK + kk * 32 + lg * 8];
            #pragma unroll
            for (int mf = 0; mf < 4; ++mf)
                #pragma unroll
                for (int nf = 0; nf < 4; ++nf)
                    acc[mf][nf] = __builtin_amdgcn_mfma_f32_16x16x32_bf16(
                        afr[mf], bfr[nf], acc[mf][nf], 0, 0, 0);
        }
        __syncthreads();
    }
    #pragma unroll
    for (int mf = 0; mf < 4; ++mf)
        #pragma unroll
        for (int j = 0; j < 4; ++j) {
            int row = bm0 + wm * 64 + mf * 16 + lg * 4 + j;
            #pragma unroll
            for (int nf = 0; nf < 4; ++nf) {
                int col = bn0 + wn * 64 + nf * 16 + l16;
                size_t idx = (size_t)row * SC_DIM + col;
                out[idx] = cur[idx] + acc[mf][nf][j];
            }
        }
}

extern "C" void kernel_launch(void* const* d_in, const int* in_sizes, int n_in,
                              void* d_out, int out_size, void* d_ws, size_t ws_size,
                              hipStream_t stream) {
    const float* proba = (const float*)d_in[0];
    const float* cur   = (const float*)d_in[1];
    const float* bsc   = (const float*)d_in[2];
    const float* avail = (const float*)d_in[3];
    const float* alloc = (const float*)d_in[4];
    float* out = (float*)d_out;

    const size_t wsA_bytes = (size_t)S_DIM * B_DIM * 2;   // 4 MB
    const size_t wsB_bytes = (size_t)SC_DIM * B_DIM * 2;  // 8 MB

    if (ws_size >= wsA_bytes + wsB_bytes) {
        unsigned short* wsA = (unsigned short*)d_ws;
        unsigned short* wsB = (unsigned short*)((char*)d_ws + wsA_bytes);

        prepack_ab<<<dim3(1024 + 512), 256, 0, stream>>>(proba, avail, alloc, bsc, wsA, wsB);
        gemm_pk<<<dim3((S_DIM / BM) * (SC_DIM / BN)), 256, 0, stream>>>(wsA, wsB, cur, out);
    } else {
        opt_gemm_fused<<<dim3(SC_DIM / FBN, S_DIM / FBM), 256, 0, stream>>>(
            proba, cur, bsc, avail, alloc, out);
    }
}